// Round 5
// baseline (340.963 us; speedup 1.0000x reference)
//
#include <hip/hip_runtime.h>

// TemporalShift: x (nt=64, c=256, h=56, w=56) fp32, t=8 segments, fold=c/8=32.
//   c in [0,32):   out[n,t] = x[n,t+1]  (zero at t==7)
//   c in [32,64):  out[n,t] = x[n,t-1]  (zero at t==0)
//   c in [64,256): out[n,t] = x[n,t]
// Pure memory-bound permuted copy.
// R1 lesson: MLP=1/wave capped us at 1.68 TB/s.
// R3 lesson: NT *loads* were wrong — harness restores d_in right before each
//   timed launch, so the input is hot in the 256 MB L3 (R1: FETCH=102 MB for a
//   205 MB input). Use cached loads; keep NT stores so the output stream does
//   not evict the input.
// R4: infra timeout, kernel unchanged — resubmitting for measurement.

typedef float f32x4 __attribute__((ext_vector_type(4)));

#define HW4        784          // (56*56)/4 vec4 per (nt,c) plane
#define CCH        256          // channels
#define FOLD       32           // c/8
#define PLANE4     (CCH * HW4)  // vec4 per nt index = 200704
#define VPT        8            // vec4 per thread
#define ELEMS_PER_BLOCK (256 * VPT)

__global__ __launch_bounds__(256) void TemporalShift_50242527428854_kernel(
    const f32x4* __restrict__ in, f32x4* __restrict__ out) {
    const int base = blockIdx.x * ELEMS_PER_BLOCK + threadIdx.x;

    int  idx[VPT];
    int  src[VPT];
    bool zf[VPT];

    // Phase 1: all address math, no memory ops
#pragma unroll
    for (int k = 0; k < VPT; ++k) {
        const int i = base + k * 256;       // 64 consecutive lanes -> coalesced
        idx[k] = i;
        const int plane = i / HW4;          // nt*256 + c  (magic-mul)
        const int c     = plane % CCH;
        const int t     = (plane / CCH) & 7;
        int  s = i;
        bool z = false;
        if (c < FOLD) {                     // take from t+1
            if (t == 7) z = true; else s = i + PLANE4;
        } else if (c < 2 * FOLD) {          // take from t-1
            if (t == 0) z = true; else s = i - PLANE4;
        }
        src[k] = s;                         // z-case keeps s=i (in-bounds)
        zf[k]  = z;
    }

    // Phase 2: 8 independent cached loads in flight
    f32x4 v[VPT];
#pragma unroll
    for (int k = 0; k < VPT; ++k) v[k] = in[src[k]];

    // Phase 3: zero-select + nontemporal store (don't pollute L3)
    const f32x4 zero = {0.f, 0.f, 0.f, 0.f};
#pragma unroll
    for (int k = 0; k < VPT; ++k) {
        const f32x4 r = zf[k] ? zero : v[k];
        __builtin_nontemporal_store(r, &out[idx[k]]);
    }
}

extern "C" void kernel_launch(void* const* d_in, const int* in_sizes, int n_in,
                              void* d_out, int out_size, void* d_ws, size_t ws_size,
                              hipStream_t stream) {
    const f32x4* in  = (const f32x4*)d_in[0];
    f32x4*       out = (f32x4*)d_out;
    const int total4 = out_size / 4;                        // 12,845,056
    const int blocks = total4 / ELEMS_PER_BLOCK;            // 6,272 exact
    TemporalShift_50242527428854_kernel<<<blocks, 256, 0, stream>>>(in, out);
}